// Round 4
// baseline (438.312 us; speedup 1.0000x reference)
//
#include <hip/hip_runtime.h>
#include <hip/hip_fp16.h>

#define N_NODES 100000
#define N_EDGES 1600000
#define FEAT 32

#define BUCKET_SHIFT 8                       // 256 nodes per bucket
#define NB 391                               // ceil(100000/256)
#define P1_BLOCKS 256
#define EPB (N_EDGES / P1_BLOCKS)            // 6250 edges per pass-1 block
#define SCAN_N (NB * P1_BLOCKS)              // 100096

// packed-fp16 pair add on int-typed storage
__device__ inline int hadd2i(int a, int b) {
    __half2 r = __hadd2(*reinterpret_cast<__half2*>(&a),
                        *reinterpret_cast<__half2*>(&b));
    return *reinterpret_cast<int*>(&r);
}

// ---------------- CSR build: 2-pass LDS-binned counting sort ----------------

__global__ __launch_bounds__(256) void bin_count(const int* __restrict__ col,
                                                 int* __restrict__ hist) {
    __shared__ int h[NB];
    int t = threadIdx.x;
    for (int i = t; i < NB; i += 256) h[i] = 0;
    __syncthreads();
    int base = blockIdx.x * EPB;
    for (int i = t; i < EPB; i += 256)
        atomicAdd(&h[col[base + i] >> BUCKET_SHIFT], 1);
    __syncthreads();
    for (int i = t; i < NB; i += 256)
        hist[i * P1_BLOCKS + blockIdx.x] = h[i];     // bucket-major
}

__global__ __launch_bounds__(1024) void scan_block(const int* __restrict__ cnt,
                                                   int* __restrict__ ex,
                                                   int* __restrict__ bsum, int n) {
    __shared__ int s[1024];
    int t = threadIdx.x;
    int i = blockIdx.x * 1024 + t;
    int v = (i < n) ? cnt[i] : 0;
    s[t] = v;
    __syncthreads();
    #pragma unroll
    for (int off = 1; off < 1024; off <<= 1) {
        int x = (t >= off) ? s[t - off] : 0;
        __syncthreads();
        s[t] += x;
        __syncthreads();
    }
    if (i < n) ex[i + 1] = s[t];
    if (t == 1023) bsum[blockIdx.x] = s[1023];
}

__global__ __launch_bounds__(128) void scan_sums(int* __restrict__ bsum, int nb) {
    __shared__ int s[128];
    int t = threadIdx.x;
    int v = (t < nb) ? bsum[t] : 0;
    s[t] = v;
    __syncthreads();
    #pragma unroll
    for (int off = 1; off < 128; off <<= 1) {
        int x = (t >= off) ? s[t - off] : 0;
        __syncthreads();
        s[t] += x;
        __syncthreads();
    }
    if (t < nb) bsum[t] = s[t] - v;       // exclusive
}

__global__ __launch_bounds__(1024) void scan_add(int* __restrict__ ex,
                                                 const int* __restrict__ bsum, int n) {
    int i = blockIdx.x * 1024 + threadIdx.x;
    if (i < n) ex[i + 1] += bsum[blockIdx.x];
    if (blockIdx.x == 0 && threadIdx.x == 0) ex[0] = 0;
}

// Pass 1c: scatter packed 4B (local_dst<<17 | src) records, bucket-ordered.
__global__ __launch_bounds__(256) void bin_scatter(const int* __restrict__ row,
                                                   const int* __restrict__ col,
                                                   const int* __restrict__ hoff,
                                                   int* __restrict__ binned) {
    __shared__ int cur[NB];
    int t = threadIdx.x;
    for (int i = t; i < NB; i += 256) cur[i] = hoff[i * P1_BLOCKS + blockIdx.x];
    __syncthreads();
    int base = blockIdx.x * EPB;
    for (int i = t; i < EPB; i += 256) {
        int c = col[base + i];
        int r = row[base + i];
        int p = atomicAdd(&cur[c >> BUCKET_SHIFT], 1);
        binned[p] = ((c & 255) << 17) | r;          // r < 2^17
    }
}

// Pass 2: one block per bucket; exclusive csrc window (no cross-XCD bouncing).
__global__ __launch_bounds__(256) void bucket_sort(const int* __restrict__ binned,
                                                   const int* __restrict__ hoff,
                                                   int* __restrict__ rp,
                                                   int* __restrict__ csrc) {
    __shared__ int h[256];
    int b = blockIdx.x, t = threadIdx.x;
    int bstart = hoff[b * P1_BLOCKS];
    int bend   = hoff[(b + 1) * P1_BLOCKS];
    h[t] = 0;
    __syncthreads();
    for (int p = bstart + t; p < bend; p += 256)
        atomicAdd(&h[binned[p] >> 17], 1);
    __syncthreads();
    int deg = h[t];
    #pragma unroll
    for (int off = 1; off < 256; off <<= 1) {       // inclusive scan
        int x = (t >= off) ? h[t - off] : 0;
        __syncthreads();
        h[t] += x;
        __syncthreads();
    }
    int mystart = bstart + h[t] - deg;
    int node = (b << BUCKET_SHIFT) + t;
    if (node < N_NODES) rp[node] = mystart;
    if (b == NB - 1 && t == 0) rp[N_NODES] = N_EDGES;
    __syncthreads();
    h[t] = mystart;                                  // cursor
    __syncthreads();
    for (int p = bstart + t; p < bend; p += 256) {
        int rec = binned[p];
        int pos = atomicAdd(&h[rec >> 17], 1);
        csrc[pos] = rec & 0x1FFFF;
    }
}

// ---------------- per-layer kernels ----------------

// m[n][f] = relu(b[f] + sum_k h[n][k] * W[k][f]), fp16 out.
// Lane f, half-wave per node; h loaded per-lane as float4 (same-line broadcast);
// W column in LDS padded transpose -> zero cross-lane ops.
__global__ __launch_bounds__(256) void node_msg_t(const float* __restrict__ h,
                                                  const float* __restrict__ W,
                                                  const float* __restrict__ b,
                                                  __half* __restrict__ m) {
    __shared__ float WsT[32 * 36];                  // WsT[f][k], stride 36
    __shared__ float bs[32];
    int t = threadIdx.x;
    for (int i = t; i < 1024; i += 256) {
        int k = i >> 5, f = i & 31;
        WsT[f * 36 + k] = W[i];
    }
    if (t < 32) bs[t] = b[t];
    __syncthreads();

    int node = blockIdx.x * 8 + (t >> 5);           // grid exact: no tail
    int f = t & 31;
    const float4* hp = (const float4*)(h + node * 32);
    const float* wr = &WsT[f * 36];
    float acc = bs[f];
    #pragma unroll
    for (int i = 0; i < 8; i++) {
        float4 q = hp[i];
        acc = fmaf(q.x, wr[4 * i + 0], acc);
        acc = fmaf(q.y, wr[4 * i + 1], acc);
        acc = fmaf(q.z, wr[4 * i + 2], acc);
        acc = fmaf(q.w, wr[4 * i + 3], acc);
    }
    m[node * 32 + f] = __float2half(fmaxf(acc, 0.f));
}

// Transposed gather: lane k owns neighbor slot k and loads its FULL 64B message
// (4x int4, 64 distinct lines in flight per wave-instruction). Packed-fp16
// shfl_xor tree reduce -> every lane holds the full aggregate -> matvec is
// per-lane (own W column from padded LDS transpose), no shuffles.
template <int OUT, bool RELU, bool RESID>
__global__ __launch_bounds__(256) void agg_out_t(const float* __restrict__ h,
                                                 const __half* __restrict__ m,
                                                 const int* __restrict__ rp,
                                                 const int* __restrict__ csrc,
                                                 const float* __restrict__ W,
                                                 const float* __restrict__ b,
                                                 float* __restrict__ out) {
    __shared__ float WsT[32 * 68];                  // WsT[f][j], j<64, stride 68
    __shared__ float bs[32];
    int t = threadIdx.x;
    for (int i = t; i < 32 * 68; i += 256) WsT[i] = 0.f;
    if (t < 32) bs[t] = (t < OUT) ? b[t] : 0.f;
    __syncthreads();
    for (int i = t; i < 64 * OUT; i += 256) {
        int j = i / OUT, f = i % OUT;
        WsT[f * 68 + j] = W[i];
    }
    __syncthreads();

    int node = blockIdx.x * 8 + (t >> 5);           // grid exact: no tail
    int k = t & 31;

    int start = rp[node];
    int end   = rp[node + 1];
    int deg   = end - start;

    int v[16];
    #pragma unroll
    for (int i = 0; i < 16; i++) v[i] = 0;          // +0.0h x2 packed

    for (int p0 = start; p0 < end; p0 += 32) {
        if (p0 + k < end) {
            int src = csrc[p0 + k];                 // coalesced 128B
            const int4* mp = (const int4*)m + src * 4;
            int4 q0 = mp[0], q1 = mp[1], q2 = mp[2], q3 = mp[3];
            v[0]  = hadd2i(v[0],  q0.x); v[1]  = hadd2i(v[1],  q0.y);
            v[2]  = hadd2i(v[2],  q0.z); v[3]  = hadd2i(v[3],  q0.w);
            v[4]  = hadd2i(v[4],  q1.x); v[5]  = hadd2i(v[5],  q1.y);
            v[6]  = hadd2i(v[6],  q1.z); v[7]  = hadd2i(v[7],  q1.w);
            v[8]  = hadd2i(v[8],  q2.x); v[9]  = hadd2i(v[9],  q2.y);
            v[10] = hadd2i(v[10], q2.z); v[11] = hadd2i(v[11], q2.w);
            v[12] = hadd2i(v[12], q3.x); v[13] = hadd2i(v[13], q3.y);
            v[14] = hadd2i(v[14], q3.z); v[15] = hadd2i(v[15], q3.w);
        }
    }

    // 5-step xor tree across the half-wave, packed fp16
    #pragma unroll
    for (int s2 = 1; s2 < 32; s2 <<= 1) {
        #pragma unroll
        for (int i = 0; i < 16; i++) {
            int o = __shfl_xor(v[i], s2, 32);
            v[i] = hadd2i(v[i], o);
        }
    }

    // per-lane matvec: lane f uses W column f
    int f = k;
    const float* wr = &WsT[f * 68];
    float accH = 0.f, accA = 0.f;
    const float4* hp = (const float4*)(h + node * 32);
    #pragma unroll
    for (int i = 0; i < 8; i++) {
        float4 q = hp[i];
        accH = fmaf(q.x, wr[4 * i + 0], accH);
        accH = fmaf(q.y, wr[4 * i + 1], accH);
        accH = fmaf(q.z, wr[4 * i + 2], accH);
        accH = fmaf(q.w, wr[4 * i + 3], accH);
    }
    #pragma unroll
    for (int i = 0; i < 16; i++) {
        float2 f2 = __half22float2(*reinterpret_cast<__half2*>(&v[i]));
        accA = fmaf(f2.x, wr[32 + 2 * i], accA);
        accA = fmaf(f2.y, wr[33 + 2 * i], accA);
    }
    float rdeg = (deg > 0) ? (1.0f / (float)deg) : 0.f;
    float r = accH + accA * rdeg + bs[f];
    if (f < OUT) {
        if (RELU) r = fmaxf(r, 0.f);
        if (RESID) r += h[node * 32 + f];
        out[node * OUT + f] = r;
    }
}

// ---------------- launch ----------------

extern "C" void kernel_launch(void* const* d_in, const int* in_sizes, int n_in,
                              void* d_out, int out_size, void* d_ws, size_t ws_size,
                              hipStream_t stream) {
    const float* x      = (const float*)d_in[0];
    const int*   ei     = (const int*)d_in[1];     // [2, E]: row then col
    const float* msg_w  = (const float*)d_in[3];   // [4,32,32]
    const float* msg_b  = (const float*)d_in[4];   // [4,32]
    const float* out_w  = (const float*)d_in[5];   // [3,64,32]
    const float* out_b  = (const float*)d_in[6];   // [3,32]
    const float* last_w = (const float*)d_in[7];   // [64,2]
    const float* last_b = (const float*)d_in[8];   // [2]
    float* coords = (float*)d_out;

    const int* row = ei;
    const int* col = ei + N_EDGES;

    // workspace carve-up; binned overlaps hA (dead until layer 0)
    float* hA  = (float*)d_ws;                      // 12.8 MB
    float* hB  = hA + N_NODES * FEAT;               // 12.8 MB
    __half* m  = (__half*)(hB + N_NODES * FEAT);    // 6.4 MB (16B aligned)
    int* rp    = (int*)(m + N_NODES * FEAT);        // [N+1]
    int* hoff  = rp + (N_NODES + 1);                // [SCAN_N+1]
    int* bsum  = hoff + (SCAN_N + 1);               // [128]
    int* hist  = bsum + 128;                        // [SCAN_N]
    int* csrc  = hist + SCAN_N;                     // [E] 6.4 MB
    int* binned = (int*)hA;                         // [E] 6.4 MB (overlap)

    const int SCAN_BLOCKS = (SCAN_N + 1023) / 1024;    // 98
    const int NODE_BLOCKS = N_NODES / 8;               // 12500 exact

    // --- build CSR (by destination), no global atomics ---
    bin_count<<<P1_BLOCKS, 256, 0, stream>>>(col, hist);
    scan_block<<<SCAN_BLOCKS, 1024, 0, stream>>>(hist, hoff, bsum, SCAN_N);
    scan_sums<<<1, 128, 0, stream>>>(bsum, SCAN_BLOCKS);
    scan_add<<<SCAN_BLOCKS, 1024, 0, stream>>>(hoff, bsum, SCAN_N);
    bin_scatter<<<P1_BLOCKS, 256, 0, stream>>>(row, col, hoff, binned);
    bucket_sort<<<NB, 256, 0, stream>>>(binned, hoff, rp, csrc);

    // --- layer 0: x -> hA ---
    node_msg_t<<<NODE_BLOCKS, 256, 0, stream>>>(x, msg_w, msg_b, m);
    agg_out_t<32, true, false><<<NODE_BLOCKS, 256, 0, stream>>>(
        x, m, rp, csrc, out_w, out_b, hA);

    // --- layer 1: hA -> hB (residual) ---
    node_msg_t<<<NODE_BLOCKS, 256, 0, stream>>>(hA, msg_w + 1024, msg_b + 32, m);
    agg_out_t<32, true, true><<<NODE_BLOCKS, 256, 0, stream>>>(
        hA, m, rp, csrc, out_w + 2048, out_b + 32, hB);

    // --- layer 2: hB -> hA (residual) ---
    node_msg_t<<<NODE_BLOCKS, 256, 0, stream>>>(hB, msg_w + 2048, msg_b + 64, m);
    agg_out_t<32, true, true><<<NODE_BLOCKS, 256, 0, stream>>>(
        hB, m, rp, csrc, out_w + 4096, out_b + 64, hA);

    // --- layer 3 (final): hA -> coords [N,2] ---
    node_msg_t<<<NODE_BLOCKS, 256, 0, stream>>>(hA, msg_w + 3072, msg_b + 96, m);
    agg_out_t<2, false, false><<<NODE_BLOCKS, 256, 0, stream>>>(
        hA, m, rp, csrc, last_w, last_b, coords);
}